// Round 5
// baseline (373.316 us; speedup 1.0000x reference)
//
#include <hip/hip_runtime.h>
#include <hip/hip_bf16.h>
#include <hip/hip_fp16.h>
#include <math.h>

#define EMB 1024
#define SEQ 2048
#define BATCH 4

typedef _Float16 half8 __attribute__((ext_vector_type(8)));
typedef float floatx4 __attribute__((ext_vector_type(4)));

__device__ __forceinline__ void gload_lds16(const void* g, void* l) {
    __builtin_amdgcn_global_load_lds(
        (const __attribute__((address_space(1))) void*)g,
        (__attribute__((address_space(3))) void*)l, 16, 0, 0);
}

// counted-vmcnt barrier: N loads may stay in flight across the barrier (T4)
__device__ __forceinline__ void bar_cnt6() {
    __builtin_amdgcn_sched_barrier(0);
    asm volatile("s_waitcnt vmcnt(6)" ::: "memory");
    __builtin_amdgcn_s_barrier();
    __builtin_amdgcn_sched_barrier(0);
}
__device__ __forceinline__ void bar_cnt3() {
    __builtin_amdgcn_sched_barrier(0);
    asm volatile("s_waitcnt vmcnt(3)" ::: "memory");
    __builtin_amdgcn_s_barrier();
    __builtin_amdgcn_sched_barrier(0);
}
__device__ __forceinline__ void bar_cnt0() {
    __builtin_amdgcn_sched_barrier(0);
    asm volatile("s_waitcnt vmcnt(0)" ::: "memory");
    __builtin_amdgcn_s_barrier();
    __builtin_amdgcn_sched_barrier(0);
}

// C[M,N] = A[M,K] * Bt[N,K]^T (fp16 row-major, K contiguous), fp32 accum.
// BM=256 BN=128 BK=32, 512 threads (8 waves: 4M x 2N, 64x64 per wave),
// ring-4 LDS (96 KiB), deep pipeline: stage T_{t+3} while computing T_t,
// vmcnt(6) at each barrier (3 loads/tile, 2 tiles in flight) -- never 0
// in the main loop.
// EPI: 0 = fp16 out + bias; 1 = fp16 out written transposed per-batch (+bias)
//      2 = fp32 out, no bias; 3 = fp32 out + bias + relu; 4 = fp16 out, no bias
template <int EPI>
__global__ __launch_bounds__(512) void gemm_p(
    const _Float16* __restrict__ A, const _Float16* __restrict__ B,
    void* __restrict__ Cv, const float* __restrict__ bias,
    int M, int N, int K, long sAb, long sBb, long sCb) {
    __shared__ _Float16 As[4][256 * 32];  // 64 KiB
    __shared__ _Float16 Bs[4][128 * 32];  // 32 KiB
    const int tid = threadIdx.x;
    const int lane = tid & 63;
    const int wave = tid >> 6;
    const long zb = blockIdx.z;
    A += zb * sAb;
    B += zb * sBb;
    const int bm = blockIdx.x * 256;
    const int bn = blockIdx.y * 128;
    floatx4 acc[4][4];
#pragma unroll
    for (int mi = 0; mi < 4; ++mi)
#pragma unroll
        for (int ni = 0; ni < 4; ++ni) acc[mi][ni] = (floatx4){0.f, 0.f, 0.f, 0.f};

    // staging map: thread stages 3 x 16B per tile (A rows 0-127, A rows
    // 128-255, B rows 0-127); LDS dest = linear tid*16B per group.
    const int srow = tid >> 2;           // 0..127
    const int scol = (tid & 3) * 8;      // 0,8,16,24
    const long ag0 = (long)(bm + srow) * K + scol;
    const long ag1 = (long)(bm + 128 + srow) * K + scol;
    const long bg0 = (long)(bn + srow) * K + scol;
    // fragment map
    const int wm = (wave >> 1) * 64;     // 0,64,128,192
    const int wn = (wave & 1) * 64;      // 0,64
    const int fr = lane & 15;
    const int fk = (lane >> 4) * 8;

#define STAGE(t_)                                                              \
    {                                                                          \
        const int b_ = (t_) & 3;                                               \
        const int kt_ = (t_) * 32;                                             \
        gload_lds16(A + ag0 + kt_, &As[b_][wave * 512]);                       \
        gload_lds16(A + ag1 + kt_, &As[b_][4096 + wave * 512]);                \
        gload_lds16(B + bg0 + kt_, &Bs[b_][wave * 512]);                       \
    }

#define COMPUTE(t_)                                                            \
    {                                                                          \
        const int b_ = (t_) & 3;                                               \
        half8 af[4], bf[4];                                                    \
        _Pragma("unroll") for (int mi = 0; mi < 4; ++mi)                       \
            af[mi] = *(const half8*)&As[b_][(wm + mi * 16 + fr) * 32 + fk];    \
        _Pragma("unroll") for (int ni = 0; ni < 4; ++ni)                       \
            bf[ni] = *(const half8*)&Bs[b_][(wn + ni * 16 + fr) * 32 + fk];    \
        _Pragma("unroll") for (int mi = 0; mi < 4; ++mi)                       \
            _Pragma("unroll") for (int ni = 0; ni < 4; ++ni)                   \
                acc[mi][ni] = __builtin_amdgcn_mfma_f32_16x16x32_f16(          \
                    af[mi], bf[ni], acc[mi][ni], 0, 0, 0);                     \
    }

    const int NT = K >> 5;  // 32 or 64 here
    STAGE(0);
    STAGE(1);
    STAGE(2);
    bar_cnt6();  // T0 arrived (6 = T1,T2 in flight)
    for (int t = 0; t < NT - 3; ++t) {
        STAGE(t + 3);   // into buffer freed at iter t-1 (post-barrier: safe)
        COMPUTE(t);
        bar_cnt6();     // T_{t+1} arrived; T_{t+2},T_{t+3} stay in flight
    }
    COMPUTE(NT - 3);
    bar_cnt3();         // T_{NT-2} arrived
    COMPUTE(NT - 2);
    bar_cnt0();         // T_{NT-1} arrived
    COMPUTE(NT - 1);
#undef STAGE
#undef COMPUTE

    const int er = (lane >> 4) * 4;
    const int ec = lane & 15;
#pragma unroll
    for (int mi = 0; mi < 4; ++mi) {
#pragma unroll
        for (int ni = 0; ni < 4; ++ni) {
            const int col = bn + wn + ni * 16 + ec;
#pragma unroll
            for (int r = 0; r < 4; ++r) {
                const int row = bm + wm + mi * 16 + er + r;
                float v = acc[mi][ni][r];
                if (EPI == 0 || EPI == 1 || EPI == 3) v += bias[col];
                if (EPI == 3) v = fmaxf(v, 0.f);
                if (EPI == 0 || EPI == 4) {
                    ((_Float16*)Cv)[zb * sCb + (long)row * N + col] = (_Float16)v;
                } else if (EPI == 1) {
                    const long b = row >> 11;      // row / SEQ
                    const long i = row & (SEQ - 1);
                    ((_Float16*)Cv)[(b * EMB + col) * SEQ + i] = (_Float16)v;
                } else {
                    ((float*)Cv)[zb * sCb + (long)row * N + col] = v;
                }
            }
        }
    }
}

// row-softmax over SEQ fp32 elements -> fp16
__global__ __launch_bounds__(256) void softmax_rows(const float* __restrict__ P,
                                                    _Float16* __restrict__ Aout) {
    const long row = blockIdx.x;
    const float* p = P + row * (long)SEQ;
    const int tid = threadIdx.x;
    float4 x0 = ((const float4*)p)[2 * tid];
    float4 x1 = ((const float4*)p)[2 * tid + 1];
    float v[8] = {x0.x, x0.y, x0.z, x0.w, x1.x, x1.y, x1.z, x1.w};
    float m = v[0];
#pragma unroll
    for (int j = 1; j < 8; ++j) m = fmaxf(m, v[j]);
#pragma unroll
    for (int o = 32; o; o >>= 1) m = fmaxf(m, __shfl_xor(m, o));
    __shared__ float rbuf[4];
    __shared__ float sbuf[4];
    const int lane = tid & 63, wv = tid >> 6;
    if (!lane) rbuf[wv] = m;
    __syncthreads();
    m = fmaxf(fmaxf(rbuf[0], rbuf[1]), fmaxf(rbuf[2], rbuf[3]));
    float s = 0.f;
#pragma unroll
    for (int j = 0; j < 8; ++j) {
        v[j] = expf(v[j] - m);
        s += v[j];
    }
#pragma unroll
    for (int o = 32; o; o >>= 1) s += __shfl_xor(s, o);
    if (!lane) sbuf[wv] = s;
    __syncthreads();
    s = sbuf[0] + sbuf[1] + sbuf[2] + sbuf[3];
    const float inv = 1.f / s;
    half8 h;
#pragma unroll
    for (int j = 0; j < 8; ++j) h[j] = (_Float16)(v[j] * inv);
    *(half8*)(Aout + row * (long)SEQ + tid * 8) = h;
}

__global__ __launch_bounds__(256) void cast_x(const float* __restrict__ X,
                                              _Float16* __restrict__ Xh) {
    const long i = (long)(blockIdx.x * 256 + threadIdx.x) * 8;
    float4 a = ((const float4*)(X + i))[0];
    float4 b = ((const float4*)(X + i))[1];
    half8 h;
    h[0] = (_Float16)a.x; h[1] = (_Float16)a.y; h[2] = (_Float16)a.z; h[3] = (_Float16)a.w;
    h[4] = (_Float16)b.x; h[5] = (_Float16)b.y; h[6] = (_Float16)b.z; h[7] = (_Float16)b.w;
    *(half8*)(Xh + i) = h;
}

// Wt[n][k] = (fp16) W[k][n]
__global__ __launch_bounds__(256) void transpose_cast(const float* __restrict__ W,
                                                      _Float16* __restrict__ Wt) {
    __shared__ float tile[32][33];
    const int bx = blockIdx.x * 32;  // n
    const int by = blockIdx.y * 32;  // k
    const int tx = threadIdx.x, ty = threadIdx.y;
#pragma unroll
    for (int r = 0; r < 32; r += 8)
        tile[ty + r][tx] = W[(long)(by + ty + r) * EMB + bx + tx];
    __syncthreads();
#pragma unroll
    for (int r = 0; r < 32; r += 8)
        Wt[(long)(bx + ty + r) * EMB + by + tx] = (_Float16)tile[tx][ty + r];
}

extern "C" void kernel_launch(void* const* d_in, const int* in_sizes, int n_in,
                              void* d_out, int out_size, void* d_ws, size_t ws_size,
                              hipStream_t stream) {
    const float* x  = (const float*)d_in[0];
    const float* Wq = (const float*)d_in[1];
    const float* bq = (const float*)d_in[2];
    const float* Wk = (const float*)d_in[3];
    const float* bk = (const float*)d_in[4];
    const float* Wv = (const float*)d_in[5];
    const float* bv = (const float*)d_in[6];
    const float* Wm = (const float*)d_in[7];
    const float* bm = (const float*)d_in[8];
    float* out = (float*)d_out;

    char* ws = (char*)d_ws;
    const long MB = 1l << 20;
    _Float16* xh  = (_Float16*)(ws + 0 * MB);    // 16 MiB
    _Float16* wqt = (_Float16*)(ws + 16 * MB);   // 2 MiB
    _Float16* wkt = (_Float16*)(ws + 18 * MB);
    _Float16* wvt = (_Float16*)(ws + 20 * MB);
    _Float16* wmt = (_Float16*)(ws + 22 * MB);
    _Float16* q   = (_Float16*)(ws + 24 * MB);   // 16 MiB
    _Float16* k   = (_Float16*)(ws + 40 * MB);   // 16 MiB
    _Float16* vt  = (_Float16*)(ws + 56 * MB);   // 16 MiB  [B][EMB][SEQ]
    _Float16* t   = (_Float16*)(ws + 72 * MB);   // 16 MiB
    float*    P   = (float*)(ws + 88 * MB);      // 64 MiB  [B][SEQ][SEQ]
    _Float16* al  = (_Float16*)(ws + 152 * MB);  // 32 MiB

    const long MN = (long)BATCH * SEQ;  // 8192 rows total

    cast_x<<<4096, 256, 0, stream>>>(x, xh);
    transpose_cast<<<dim3(32, 32), dim3(32, 8), 0, stream>>>(Wq, wqt);
    transpose_cast<<<dim3(32, 32), dim3(32, 8), 0, stream>>>(Wk, wkt);
    transpose_cast<<<dim3(32, 32), dim3(32, 8), 0, stream>>>(Wv, wvt);
    transpose_cast<<<dim3(32, 32), dim3(32, 8), 0, stream>>>(Wm, wmt);

    // q = x@Wq + bq ; k = x@Wk + bk ; v = x@Wv + bv (written transposed per batch)
    gemm_p<0><<<dim3(32, 8), 512, 0, stream>>>(xh, wqt, q, bq, (int)MN, EMB, EMB, 0, 0, 0);
    gemm_p<0><<<dim3(32, 8), 512, 0, stream>>>(xh, wkt, k, bk, (int)MN, EMB, EMB, 0, 0, 0);
    gemm_p<1><<<dim3(32, 8), 512, 0, stream>>>(xh, wvt, vt, bv, (int)MN, EMB, EMB, 0, 0, 0);

    // P[b][j][i] = k_j . q_i
    gemm_p<2><<<dim3(8, 16, BATCH), 512, 0, stream>>>(
        k, q, P, nullptr, SEQ, SEQ, EMB,
        (long)SEQ * EMB, (long)SEQ * EMB, (long)SEQ * SEQ);

    // alpha = row-softmax(P)  (softmax over i)
    softmax_rows<<<BATCH * SEQ, 256, 0, stream>>>(P, al);

    // t[b][j][d] = sum_i alpha[j][i] * vt[d][i]
    gemm_p<4><<<dim3(8, 8, BATCH), 512, 0, stream>>>(
        al, vt, t, nullptr, SEQ, EMB, SEQ,
        (long)SEQ * SEQ, (long)EMB * SEQ, (long)SEQ * EMB);

    // out = relu(t @ Wm + bm)
    gemm_p<3><<<dim3(32, 8), 512, 0, stream>>>(t, wmt, out, bm, (int)MN, EMB, EMB, 0, 0, 0);
}

// Round 7
// 303.335 us; speedup vs baseline: 1.2307x; 1.2307x over previous
//
#include <hip/hip_runtime.h>
#include <hip/hip_bf16.h>
#include <hip/hip_fp16.h>
#include <math.h>

#define EMB 1024
#define SEQ 2048
#define BATCH 4

typedef _Float16 half8 __attribute__((ext_vector_type(8)));
typedef float floatx4 __attribute__((ext_vector_type(4)));

__device__ __forceinline__ void gload_lds16(const void* g, void* l) {
    __builtin_amdgcn_global_load_lds(
        (const __attribute__((address_space(1))) void*)g,
        (__attribute__((address_space(3))) void*)l, 16, 0, 0);
}

__device__ __forceinline__ void sbar() {
    __builtin_amdgcn_sched_barrier(0);
    __builtin_amdgcn_s_barrier();
    __builtin_amdgcn_sched_barrier(0);
}

// C[M,N] = A[M,K] * Bt[N,K]^T (fp16 row-major, K contiguous), fp32 accum.
// 8-phase-style schedule (T2+T3+T4+T5): BM=256 BN=128 BK=64, 512 thr (8 waves,
// 4Mx2N, 64x64/wave). Ring-3 LDS (144 KiB), prefetch distance 2, vmcnt(6) once
// per K-tile (never 0 in main loop). Per phase: 8 ds_read_b128 + 3
// global_load_lds + barrier + lgkmcnt(0) + setprio-wrapped 16 MFMA + barrier.
// T2 swizzle: 16B slot ^= (row&7); linear LDS dest + pre-swizzled global src.
// EPI: 0 = fp16 out + bias; 1 = fp16 out transposed per-batch (+bias)
//      2 = fp32 out, no bias; 3 = fp32 out + bias + relu; 4 = fp16 out, no bias
template <int EPI>
__global__ __launch_bounds__(512) void gemm_8p(
    const _Float16* __restrict__ A, const _Float16* __restrict__ B,
    void* __restrict__ Cv, const float* __restrict__ bias,
    int M, int N, int K, long sAb, long sBb, long sCb) {
    // per buffer: A 256x64 (16384 elems) + B 128x64 (8192 elems) = 48 KiB
    __shared__ _Float16 lds[3 * 24576];  // 144 KiB
    const int tid = threadIdx.x;
    const int lane = tid & 63;
    const int wave = tid >> 6;
    const long zb = blockIdx.z;
    A += zb * sAb;
    B += zb * sBb;
    const int bm = blockIdx.x * 256;
    const int bn = blockIdx.y * 128;
    floatx4 acc[4][4];
#pragma unroll
    for (int mi = 0; mi < 4; ++mi)
#pragma unroll
        for (int ni = 0; ni < 4; ++ni) acc[mi][ni] = (floatx4){0.f, 0.f, 0.f, 0.f};

    // staging: thread stages 16B slots; physical slot tid&7 of row i*64+(tid>>3)
    // source col pre-swizzled: logical slot = phys ^ (row&7)
    const int srow = tid >> 3;                 // 0..63
    const int ssl = (tid & 7) ^ (srow & 7);    // swizzled slot
    const _Float16* Ag = A + (long)(bm + srow) * K + ssl * 8;
    const _Float16* Bg = B + (long)(bn + srow) * K + ssl * 8;
    const long K64 = (long)K * 64;
    const int ldst = wave * 512;

    // fragment reads: row = w? + mi*16 + (lane&15); phys slot = (P*4+g) ^ (lane&7)
    const int wm = (wave >> 1) * 64;
    const int wn = (wave & 1) * 64;
    const int l15 = lane & 15;
    const int x7 = lane & 7;
    const int g4 = lane >> 4;
    const int sl0 = (g4 ^ x7) * 8;
    const int sl1 = ((4 + g4) ^ x7) * 8;
    const int fA0 = (wm + l15) * 64 + sl0;
    const int fA1 = (wm + l15) * 64 + sl1;
    const int fB0 = 16384 + (wn + l15) * 64 + sl0;
    const int fB1 = 16384 + (wn + l15) * 64 + sl1;

#define STG_H0(kt_, so_)                                                       \
    gload_lds16(Ag + (kt_), &lds[(so_) + ldst]);                               \
    gload_lds16(Ag + K64 + (kt_), &lds[(so_) + 4096 + ldst]);                  \
    gload_lds16(Bg + (kt_), &lds[(so_) + 16384 + ldst]);
#define STG_H1(kt_, so_)                                                       \
    gload_lds16(Ag + 2 * K64 + (kt_), &lds[(so_) + 8192 + ldst]);              \
    gload_lds16(Ag + 3 * K64 + (kt_), &lds[(so_) + 12288 + ldst]);             \
    gload_lds16(Bg + K64 + (kt_), &lds[(so_) + 16384 + 4096 + ldst]);

#define PHASE(fa_, fb_, co_, STG_)                                             \
    {                                                                          \
        half8 af[4], bf[4];                                                    \
        _Pragma("unroll") for (int mi = 0; mi < 4; ++mi)                       \
            af[mi] = *(const half8*)&lds[(co_) + (fa_) + mi * 1024];           \
        _Pragma("unroll") for (int ni = 0; ni < 4; ++ni)                       \
            bf[ni] = *(const half8*)&lds[(co_) + (fb_) + ni * 1024];           \
        STG_                                                                   \
        sbar();                                                                \
        asm volatile("s_waitcnt lgkmcnt(0)" ::: "memory");                     \
        __builtin_amdgcn_sched_barrier(0);                                     \
        __builtin_amdgcn_s_setprio(1);                                         \
        _Pragma("unroll") for (int mi = 0; mi < 4; ++mi)                       \
            _Pragma("unroll") for (int ni = 0; ni < 4; ++ni)                   \
                acc[mi][ni] = __builtin_amdgcn_mfma_f32_16x16x32_f16(          \
                    af[mi], bf[ni], acc[mi][ni], 0, 0, 0);                     \
        __builtin_amdgcn_s_setprio(0);                                         \
    }

#define TILE_END(n_)                                                           \
    __builtin_amdgcn_sched_barrier(0);                                         \
    asm volatile("s_waitcnt vmcnt(" #n_ ")" ::: "memory");                     \
    __builtin_amdgcn_s_barrier();                                              \
    __builtin_amdgcn_sched_barrier(0);

    // prologue: stage tiles 0 (buf0) and 1 (buf1)
    STG_H0(0, 0) STG_H1(0, 0)
    STG_H0(64, 24576) STG_H1(64, 24576)
    TILE_END(6)  // tile 0 landed; tile 1 in flight
    int co = 0, so = 49152;
    const int NT = K >> 6;
    for (int t = 0; t < NT - 2; ++t) {
        const long kt2 = (long)(t + 2) << 6;
        PHASE(fA0, fB0, co, STG_H0(kt2, so))
        sbar();
        PHASE(fA1, fB1, co, STG_H1(kt2, so))
        TILE_END(6)  // tile t+1 landed; t+2 stays in flight
        co += 24576; if (co == 73728) co = 0;
        so += 24576; if (so == 73728) so = 0;
    }
    // t = NT-2: no stage; tile NT-1 still in flight
    PHASE(fA0, fB0, co, )
    sbar();
    PHASE(fA1, fB1, co, )
    TILE_END(0)  // tile NT-1 landed
    co += 24576; if (co == 73728) co = 0;
    // t = NT-1
    PHASE(fA0, fB0, co, )
    sbar();
    PHASE(fA1, fB1, co, )
#undef STG_H0
#undef STG_H1
#undef PHASE
#undef TILE_END

    const int er = (lane >> 4) * 4;
    const int ec = lane & 15;
#pragma unroll
    for (int mi = 0; mi < 4; ++mi) {
#pragma unroll
        for (int ni = 0; ni < 4; ++ni) {
            const int col = bn + wn + ni * 16 + ec;
#pragma unroll
            for (int r = 0; r < 4; ++r) {
                const int row = bm + wm + mi * 16 + er + r;
                float v = acc[mi][ni][r];
                if (EPI == 0 || EPI == 1 || EPI == 3) v += bias[col];
                if (EPI == 3) v = fmaxf(v, 0.f);
                if (EPI == 0 || EPI == 4) {
                    ((_Float16*)Cv)[zb * sCb + (long)row * N + col] = (_Float16)v;
                } else if (EPI == 1) {
                    const long b = row >> 11;      // row / SEQ
                    const long i = row & (SEQ - 1);
                    ((_Float16*)Cv)[(b * EMB + col) * SEQ + i] = (_Float16)v;
                } else {
                    ((float*)Cv)[zb * sCb + (long)row * N + col] = v;
                }
            }
        }
    }
}

// row-softmax over SEQ fp32 elements -> fp16
__global__ __launch_bounds__(256) void softmax_rows(const float* __restrict__ P,
                                                    _Float16* __restrict__ Aout) {
    const long row = blockIdx.x;
    const float* p = P + row * (long)SEQ;
    const int tid = threadIdx.x;
    float4 x0 = ((const float4*)p)[2 * tid];
    float4 x1 = ((const float4*)p)[2 * tid + 1];
    float v[8] = {x0.x, x0.y, x0.z, x0.w, x1.x, x1.y, x1.z, x1.w};
    float m = v[0];
#pragma unroll
    for (int j = 1; j < 8; ++j) m = fmaxf(m, v[j]);
#pragma unroll
    for (int o = 32; o; o >>= 1) m = fmaxf(m, __shfl_xor(m, o));
    __shared__ float rbuf[4];
    __shared__ float sbuf[4];
    const int lane = tid & 63, wv = tid >> 6;
    if (!lane) rbuf[wv] = m;
    __syncthreads();
    m = fmaxf(fmaxf(rbuf[0], rbuf[1]), fmaxf(rbuf[2], rbuf[3]));
    float s = 0.f;
#pragma unroll
    for (int j = 0; j < 8; ++j) {
        v[j] = expf(v[j] - m);
        s += v[j];
    }
#pragma unroll
    for (int o = 32; o; o >>= 1) s += __shfl_xor(s, o);
    if (!lane) sbuf[wv] = s;
    __syncthreads();
    s = sbuf[0] + sbuf[1] + sbuf[2] + sbuf[3];
    const float inv = 1.f / s;
    half8 h;
#pragma unroll
    for (int j = 0; j < 8; ++j) h[j] = (_Float16)(v[j] * inv);
    *(half8*)(Aout + row * (long)SEQ + tid * 8) = h;
}

__global__ __launch_bounds__(256) void cast_x(const float* __restrict__ X,
                                              _Float16* __restrict__ Xh) {
    const long i = (long)(blockIdx.x * 256 + threadIdx.x) * 8;
    float4 a = ((const float4*)(X + i))[0];
    float4 b = ((const float4*)(X + i))[1];
    half8 h;
    h[0] = (_Float16)a.x; h[1] = (_Float16)a.y; h[2] = (_Float16)a.z; h[3] = (_Float16)a.w;
    h[4] = (_Float16)b.x; h[5] = (_Float16)b.y; h[6] = (_Float16)b.z; h[7] = (_Float16)b.w;
    *(half8*)(Xh + i) = h;
}

// Wt[n][k] = (fp16) W[k][n]
__global__ __launch_bounds__(256) void transpose_cast(const float* __restrict__ W,
                                                      _Float16* __restrict__ Wt) {
    __shared__ float tile[32][33];
    const int bx = blockIdx.x * 32;  // n
    const int by = blockIdx.y * 32;  // k
    const int tx = threadIdx.x, ty = threadIdx.y;
#pragma unroll
    for (int r = 0; r < 32; r += 8)
        tile[ty + r][tx] = W[(long)(by + ty + r) * EMB + bx + tx];
    __syncthreads();
#pragma unroll
    for (int r = 0; r < 32; r += 8)
        Wt[(long)(bx + ty + r) * EMB + by + tx] = (_Float16)tile[tx][ty + r];
}

extern "C" void kernel_launch(void* const* d_in, const int* in_sizes, int n_in,
                              void* d_out, int out_size, void* d_ws, size_t ws_size,
                              hipStream_t stream) {
    const float* x  = (const float*)d_in[0];
    const float* Wq = (const float*)d_in[1];
    const float* bq = (const float*)d_in[2];
    const float* Wk = (const float*)d_in[3];
    const float* bk = (const float*)d_in[4];
    const float* Wv = (const float*)d_in[5];
    const float* bv = (const float*)d_in[6];
    const float* Wm = (const float*)d_in[7];
    const float* bm = (const float*)d_in[8];
    float* out = (float*)d_out;

    char* ws = (char*)d_ws;
    const long MB = 1l << 20;
    _Float16* xh  = (_Float16*)(ws + 0 * MB);    // 16 MiB
    _Float16* wqt = (_Float16*)(ws + 16 * MB);   // 2 MiB
    _Float16* wkt = (_Float16*)(ws + 18 * MB);
    _Float16* wvt = (_Float16*)(ws + 20 * MB);
    _Float16* wmt = (_Float16*)(ws + 22 * MB);
    _Float16* q   = (_Float16*)(ws + 24 * MB);   // 16 MiB
    _Float16* k   = (_Float16*)(ws + 40 * MB);   // 16 MiB
    _Float16* vt  = (_Float16*)(ws + 56 * MB);   // 16 MiB  [B][EMB][SEQ]
    _Float16* t   = (_Float16*)(ws + 72 * MB);   // 16 MiB
    float*    P   = (float*)(ws + 88 * MB);      // 64 MiB  [B][SEQ][SEQ]
    _Float16* al  = (_Float16*)(ws + 152 * MB);  // 32 MiB

    const long MN = (long)BATCH * SEQ;  // 8192 rows total

    cast_x<<<4096, 256, 0, stream>>>(x, xh);
    transpose_cast<<<dim3(32, 32), dim3(32, 8), 0, stream>>>(Wq, wqt);
    transpose_cast<<<dim3(32, 32), dim3(32, 8), 0, stream>>>(Wk, wkt);
    transpose_cast<<<dim3(32, 32), dim3(32, 8), 0, stream>>>(Wv, wvt);
    transpose_cast<<<dim3(32, 32), dim3(32, 8), 0, stream>>>(Wm, wmt);

    // q = x@Wq + bq ; k = x@Wk + bk ; v = x@Wv + bv (written transposed per batch)
    gemm_8p<0><<<dim3(32, 8), 512, 0, stream>>>(xh, wqt, q, bq, (int)MN, EMB, EMB, 0, 0, 0);
    gemm_8p<0><<<dim3(32, 8), 512, 0, stream>>>(xh, wkt, k, bk, (int)MN, EMB, EMB, 0, 0, 0);
    gemm_8p<1><<<dim3(32, 8), 512, 0, stream>>>(xh, wvt, vt, bv, (int)MN, EMB, EMB, 0, 0, 0);

    // P[b][j][i] = k_j . q_i
    gemm_8p<2><<<dim3(8, 16, BATCH), 512, 0, stream>>>(
        k, q, P, nullptr, SEQ, SEQ, EMB,
        (long)SEQ * EMB, (long)SEQ * EMB, (long)SEQ * SEQ);

    // alpha = row-softmax(P)  (softmax over i)
    softmax_rows<<<BATCH * SEQ, 256, 0, stream>>>(P, al);

    // t[b][j][d] = sum_i alpha[j][i] * vt[d][i]
    gemm_8p<4><<<dim3(8, 8, BATCH), 512, 0, stream>>>(
        al, vt, t, nullptr, SEQ, EMB, SEQ,
        (long)SEQ * SEQ, (long)EMB * SEQ, (long)SEQ * EMB);

    // out = relu(t @ Wm + bm)
    gemm_8p<3><<<dim3(32, 8), 512, 0, stream>>>(t, wmt, out, bm, (int)MN, EMB, EMB, 0, 0, 0);
}